// Round 9
// baseline (388.754 us; speedup 1.0000x reference)
//
#include <hip/hip_runtime.h>
#include <hip/hip_bf16.h>

typedef unsigned short u16;
typedef __attribute__((ext_vector_type(8))) short bf16x8;   // 8 bf16 = 4 VGPRs (MFMA A/B operand)
typedef __attribute__((ext_vector_type(4))) float f32x4;    // 16x16 MFMA C/D
typedef __attribute__((ext_vector_type(16))) float f32x16;  // 32x32 MFMA C/D
typedef __attribute__((ext_vector_type(4))) u16 u16x4;
typedef __attribute__((ext_vector_type(2))) int i32x2;
typedef __attribute__((ext_vector_type(4))) int i32x4;

#define DEV __device__ __forceinline__

constexpr int B_ = 4, S_ = 2048, H_ = 16, DK_ = 64, DM_ = 1024;
constexpr int M_ = B_ * S_;  // 8192 rows per GEMM

DEV u16 f2bf(float x) {  // RNE fp32 -> bf16
  union { float f; unsigned u; } v; v.f = x;
  return (u16)((v.u + 0x7fffu + ((v.u >> 16) & 1u)) >> 16);
}

DEV bf16x8 ld16(const u16* p) { return *(const bf16x8*)p; }

DEV void g2l16(const void* g, void* l) {  // async global->LDS, 16B/lane, wave-uniform dest
  __builtin_amdgcn_global_load_lds((const __attribute__((address_space(1))) void*)g,
                                   (__attribute__((address_space(3))) void*)l, 16, 0, 0);
}

DEV int cvtpk(float lo, float hi) {  // packed bf16 pair (RNE)
  int r;
  asm("v_cvt_pk_bf16_f32 %0, %1, %2" : "=v"(r) : "v"(lo), "v"(hi));
  return r;
}

DEV i32x2 pl32swap(int a, int b) {
  return __builtin_amdgcn_permlane32_swap(a, b, false, false);
}

DEV float asf(int x) { return __builtin_bit_cast(float, x); }
DEV int asi(float x) { return __builtin_bit_cast(int, x); }

// ---------------- weight transpose-convert: W[K][N] fp32 -> Wt[N][K] bf16 ----------------
__global__ __launch_bounds__(256) void wtrans_kernel(const float* __restrict__ W,
                                                     u16* __restrict__ Wt) {
  __shared__ u16 t[64][68];
  const int r0 = blockIdx.y * 64, c0 = blockIdx.x * 64;
  const int lr = threadIdx.x >> 4;
  const int lc = (threadIdx.x & 15) * 4;
#pragma unroll
  for (int i = 0; i < 4; ++i) {
    int row = i * 16 + lr;
    float4 v = *(const float4*)(W + (size_t)(r0 + row) * DM_ + c0 + lc);
    t[lc + 0][row] = f2bf(v.x); t[lc + 1][row] = f2bf(v.y);
    t[lc + 2][row] = f2bf(v.z); t[lc + 3][row] = f2bf(v.w);
  }
  __syncthreads();
#pragma unroll
  for (int i = 0; i < 4; ++i) {
    int c = i * 16 + lr;
    u16x4 o; o[0] = t[c][lc]; o[1] = t[c][lc + 1]; o[2] = t[c][lc + 2]; o[3] = t[c][lc + 3];
    *(u16x4*)(Wt + (size_t)(c0 + c) * DM_ + r0 + lc) = o;
  }
}

// ================= 128x128 GEMM, BK=64, 4 waves, lead-1 async double-buffer =================
// KIND 0: batched QKV (1536 blocks, 6/CU). A = fp32 (cvt fused, reg-staged, loads issued
//         BEFORE B-DMA so the A-write waits vmcnt(4), leaving B-DMA in flight).
//         sel 0,1 -> bf16 scatter [b][h][s][d]; sel 2 -> bf16 scatter [b][h][d][s].
// KIND 1: out-proj (512 blocks, 2/CU exactly). A = bf16 ctx via DMA. fp32 row-major out.
// T2 swizzle: 16B chunk c stored at c ^ (row&7) (both sides); conflict-free ds_read_b128.
template <int KIND>
__global__ __launch_bounds__(256, 2) void gemm128(const float* __restrict__ x0f,
                                                  const float* __restrict__ x1f,
                                                  const float* __restrict__ x2f,
                                                  const u16* __restrict__ xb,
                                                  const u16* __restrict__ w0,
                                                  const u16* __restrict__ w1,
                                                  const u16* __restrict__ w2,
                                                  void* __restrict__ o0,
                                                  void* __restrict__ o1,
                                                  void* __restrict__ o2) {
  constexpr int K = 1024, NK = 16;  // 16 K-tiles of 64
  __shared__ u16 As[2][8192];       // [slot][128 rows][64 cols] bf16, 16KB/slot
  __shared__ u16 Bs[2][8192];
  const int tid = threadIdx.x;
  const int w = tid >> 6, lane = tid & 63;
  const int l15 = lane & 15, lg = (lane >> 4) & 3;
  const int sr = tid >> 3;          // staging row-within-32 (0..31)
  const int c8 = tid & 7;           // staging chunk
  const int cg = c8 ^ (sr & 7);     // swizzled source/write chunk (row&7 == sr&7)

  // ---- bijective XCD swizzle (gridDim.x % 8 == 0)
  const int wg = blockIdx.x;
  const int cpx = gridDim.x >> 3;
  const int idx = (wg & 7) * cpx + (wg >> 3);
  const int sel = (KIND == 0) ? (idx >> 9) : 0;     // 512 blocks per input
  const int rid = (KIND == 0) ? (idx & 511) : idx;
  const int mblk = rid >> 3, nblk = rid & 7;
  const int m0 = mblk * 128, n0 = nblk * 128;

  const float* Xf = nullptr;
  const u16* Wt;
  if (KIND == 0) {
    Xf = sel == 0 ? x0f : sel == 1 ? x1f : x2f;
    Wt = sel == 0 ? w0 : sel == 1 ? w1 : w2;
  } else {
    Wt = w0;
  }

  // wave tiling: 2x2 waves, each 64x64 output = 4x4 frags of 16x16
  const int wm = (w >> 1) * 64, wn = (w & 1) * 64;
  f32x4 acc[4][4] = {};

  // ---- prologue: stage K-tile 0 -> slot 0
  {
#pragma unroll
    for (int j = 0; j < 4; ++j) {
      int r = j * 32 + sr;
      g2l16(Wt + (size_t)(n0 + r) * K + cg * 8, &Bs[0][(j * 32 + 8 * w) * 64]);
    }
    if (KIND == 0) {
#pragma unroll
      for (int j = 0; j < 4; ++j) {
        int r = j * 32 + sr;
        const float* src = Xf + (size_t)(m0 + r) * K + c8 * 8;
        float4 u = *(const float4*)src, v2 = *(const float4*)(src + 4);
        i32x4 pk = {cvtpk(u.x, u.y), cvtpk(u.z, u.w), cvtpk(v2.x, v2.y), cvtpk(v2.z, v2.w)};
        *(i32x4*)(&As[0][r * 64 + cg * 8]) = pk;
      }
    } else {
#pragma unroll
      for (int j = 0; j < 4; ++j) {
        int r = j * 32 + sr;
        g2l16(xb + (size_t)(m0 + r) * K + cg * 8, &As[0][(j * 32 + 8 * w) * 64]);
      }
    }
  }

  for (int g = 0; g < NK; ++g) {
    // ---- boundary: tile g landed (DMA issued a full compute phase ago)
    asm volatile("s_waitcnt vmcnt(0) lgkmcnt(0)" ::: "memory");
    __builtin_amdgcn_s_barrier();
    asm volatile("" ::: "memory");
    const int rs = g & 1, ws2 = (g + 1) & 1;
    const bool st = (g + 1) < NK;
    const int kt1 = (g + 1) * 64;

    // ---- issue next-tile staging. KIND0: A-loads FIRST (oldest) so the deferred
    //      A-write waits vmcnt(4), leaving B-DMA in flight across the next barrier.
    float4 au[4], av[4];
    if (st) {
      if (KIND == 0) {
#pragma unroll
        for (int j = 0; j < 4; ++j) {
          int r = j * 32 + sr;
          const float* src = Xf + (size_t)(m0 + r) * K + kt1 + c8 * 8;
          au[j] = *(const float4*)src;
          av[j] = *(const float4*)(src + 4);
        }
      }
#pragma unroll
      for (int j = 0; j < 4; ++j) {
        int r = j * 32 + sr;
        g2l16(Wt + (size_t)(n0 + r) * K + kt1 + cg * 8, &Bs[ws2][(j * 32 + 8 * w) * 64]);
      }
      if (KIND == 1) {
#pragma unroll
        for (int j = 0; j < 4; ++j) {
          int r = j * 32 + sr;
          g2l16(xb + (size_t)(m0 + r) * K + kt1 + cg * 8, &As[ws2][(j * 32 + 8 * w) * 64]);
        }
      }
    }

    // ---- compute: 2 k-slots x 16 MFMA, swizzled conflict-free ds_read_b128
#pragma unroll
    for (int kk = 0; kk < 2; ++kk) {
      bf16x8 af[4], bfr[4];
      const int ck = (kk * 4 + lg) ^ (l15 & 7);
#pragma unroll
      for (int mf = 0; mf < 4; ++mf)
        af[mf] = ld16(&As[rs][(wm + mf * 16 + l15) * 64 + ck * 8]);
#pragma unroll
      for (int nf = 0; nf < 4; ++nf)
        bfr[nf] = ld16(&Bs[rs][(wn + nf * 16 + l15) * 64 + ck * 8]);
      __builtin_amdgcn_s_setprio(1);
#pragma unroll
      for (int mf = 0; mf < 4; ++mf)
#pragma unroll
        for (int nf = 0; nf < 4; ++nf)
          acc[mf][nf] = __builtin_amdgcn_mfma_f32_16x16x32_bf16(af[mf], bfr[nf], acc[mf][nf], 0, 0, 0);
      __builtin_amdgcn_s_setprio(0);
    }

    // ---- deferred A-write (waits only the A-loads: vmcnt(4))
    if (KIND == 0 && st) {
      __builtin_amdgcn_sched_barrier(0);
#pragma unroll
      for (int j = 0; j < 4; ++j) {
        int r = j * 32 + sr;
        float4 u = au[j], v2 = av[j];
        i32x4 pk = {cvtpk(u.x, u.y), cvtpk(u.z, u.w), cvtpk(v2.x, v2.y), cvtpk(v2.z, v2.w)};
        *(i32x4*)(&As[ws2][r * 64 + cg * 8]) = pk;
      }
    }
  }

  // ---- epilogue: C/D layout col=lane&15, row=(lane>>4)*4+r  [m89-verified]
#pragma unroll
  for (int mf = 0; mf < 4; ++mf)
#pragma unroll
    for (int nf = 0; nf < 4; ++nf) {
      if (KIND == 0 && sel == 2) {
        int m = m0 + wm + mf * 16 + lg * 4;
        int n = n0 + wn + nf * 16 + l15;
        int b = m >> 11, s = m & 2047;
        int h = n >> 6, d = n & 63;
        u16x4 o;
#pragma unroll
        for (int r = 0; r < 4; ++r) o[r] = f2bf(acc[mf][nf][r]);
        *(u16x4*)((u16*)o2 + ((size_t)(b * H_ + h) * DK_ + d) * S_ + s) = o;
      } else if (KIND == 0) {
        u16* op = (u16*)(sel == 0 ? o0 : o1);
#pragma unroll
        for (int r = 0; r < 4; ++r) {
          int m = m0 + wm + mf * 16 + lg * 4 + r;
          int n = n0 + wn + nf * 16 + l15;
          int b = m >> 11, s = m & 2047;
          int h = n >> 6, d = n & 63;
          op[((size_t)(b * H_ + h) * S_ + s) * DK_ + d] = f2bf(acc[mf][nf][r]);
        }
      } else {
#pragma unroll
        for (int r = 0; r < 4; ++r) {
          int m = m0 + wm + mf * 16 + lg * 4 + r;
          int n = n0 + wn + nf * 16 + l15;
          ((float*)o0)[(size_t)m * DM_ + n] = acc[mf][nf][r];
        }
      }
    }
}

// ---------------- flash attention: LDS-staged K/V (lead-1 dbuf) + in-reg softmax ----------
// (unchanged from round 8 — measured 134.5us, MfmaUtil 21.9%, VALUBusy 69%)
__global__ __launch_bounds__(256, 4) void attn_kernel(const u16* __restrict__ Qh,
                                                      const u16* __restrict__ Kh,
                                                      const u16* __restrict__ Vt,
                                                      u16* __restrict__ ctx) {
  __shared__ u16 KV[2][2][4096];  // [slot][K/V][64 rows x 64 cols], 32 KB
  const int tid = threadIdx.x;
  const int lane = tid & 63, w = tid >> 6;
  const int l31 = lane & 31, hi = lane >> 5;
  const int bh = blockIdx.y;
  const int q0 = blockIdx.x * 128 + w * 32;

  const u16* Qb = Qh + (size_t)bh * S_ * DK_;
  const u16* Kb = Kh + (size_t)bh * S_ * DK_;
  const u16* Vb = Vt + (size_t)bh * DK_ * S_;

  const int srow = tid >> 3;
  const int cs = (tid & 7) ^ (srow & 7);
  const int dstoff = w * 512;

  bf16x8 qf[4];
#pragma unroll
  for (int ds = 0; ds < 4; ++ds)
    qf[ds] = ld16(Qb + (size_t)(q0 + l31) * DK_ + ds * 16 + hi * 8);

  f32x16 accO[2] = {};
  float mreg = -1e30f, lsum = 0.f;
  const float SC = 0.125f * 1.44269504088896f;
  const int swz = (l31 & 7);

#pragma unroll
  for (int j = 0; j < 2; ++j) {
    int r = j * 32 + srow;
    g2l16(Kb + (size_t)r * DK_ + cs * 8, &KV[0][0][j * 2048 + dstoff]);
    g2l16(Vb + (size_t)r * S_ + cs * 8, &KV[0][1][j * 2048 + dstoff]);
  }

  for (int i = 0; i < 32; ++i) {
    const int cur = i & 1, nxt = cur ^ 1;
    __syncthreads();
    if (i < 31) {
      const int kvn = (i + 1) * 64;
#pragma unroll
      for (int j = 0; j < 2; ++j) {
        int r = j * 32 + srow;
        g2l16(Kb + (size_t)(kvn + r) * DK_ + cs * 8, &KV[nxt][0][j * 2048 + dstoff]);
        g2l16(Vb + (size_t)r * S_ + kvn + cs * 8, &KV[nxt][1][j * 2048 + dstoff]);
      }
    }

    f32x16 accS[2] = {};
    __builtin_amdgcn_s_setprio(1);
#pragma unroll
    for (int t = 0; t < 2; ++t)
#pragma unroll
      for (int ds = 0; ds < 4; ++ds) {
        bf16x8 kf = ld16(&KV[cur][0][(t * 32 + l31) * 64 + (((ds * 2 + hi) ^ swz) * 8)]);
        accS[t] = __builtin_amdgcn_mfma_f32_32x32x16_bf16(kf, qf[ds], accS[t], 0, 0, 0);
      }
    __builtin_amdgcn_s_setprio(0);

    float a[8];
#pragma unroll
    for (int r = 0; r < 8; ++r)
      a[r] = fmaxf(fmaxf(accS[0][r], accS[1][r]), fmaxf(accS[0][r + 8], accS[1][r + 8]));
#pragma unroll
    for (int s = 4; s; s >>= 1)
#pragma unroll
      for (int r = 0; r < s; ++r) a[r] = fmaxf(a[r], a[r + s]);
    i32x2 mm = pl32swap(asi(a[0]), asi(a[0]));
    float mx = fmaxf(asf(mm.x), asf(mm.y)) * SC;
    if (__any(mx > mreg + 8.f)) {
      float mnew = fmaxf(mreg, mx);
      float scl = exp2f(mreg - mnew);
      mreg = mnew;
      lsum *= scl;
#pragma unroll
      for (int r = 0; r < 16; ++r) { accO[0][r] *= scl; accO[1][r] *= scl; }
    }
#pragma unroll
    for (int t = 0; t < 2; ++t)
#pragma unroll
      for (int r = 0; r < 16; ++r)
        accS[t][r] = exp2f(fmaf(accS[t][r], SC, -mreg));
#pragma unroll
    for (int r = 0; r < 8; ++r)
      a[r] = (accS[0][r] + accS[1][r]) + (accS[0][r + 8] + accS[1][r + 8]);
#pragma unroll
    for (int s = 4; s; s >>= 1)
#pragma unroll
      for (int r = 0; r < s; ++r) a[r] += a[r + s];
    i32x2 ss = pl32swap(asi(a[0]), asi(a[0]));
    lsum += asf(ss.x) + asf(ss.y);

    bf16x8 pb[4];
#pragma unroll
    for (int t = 0; t < 2; ++t) {
      i32x2 sA = pl32swap(cvtpk(accS[t][0], accS[t][1]), cvtpk(accS[t][4], accS[t][5]));
      i32x2 sB = pl32swap(cvtpk(accS[t][2], accS[t][3]), cvtpk(accS[t][6], accS[t][7]));
      i32x2 sC = pl32swap(cvtpk(accS[t][8], accS[t][9]), cvtpk(accS[t][12], accS[t][13]));
      i32x2 sD = pl32swap(cvtpk(accS[t][10], accS[t][11]), cvtpk(accS[t][14], accS[t][15]));
      union { i32x4 i; bf16x8 h; } u0, u1;
      u0.i = (i32x4){sA.x, sB.x, sA.y, sB.y};
      u1.i = (i32x4){sC.x, sD.x, sC.y, sD.y};
      pb[2 * t] = u0.h;
      pb[2 * t + 1] = u1.h;
    }

    __builtin_amdgcn_s_setprio(1);
#pragma unroll
    for (int ks = 0; ks < 4; ++ks)
#pragma unroll
      for (int dh = 0; dh < 2; ++dh) {
        bf16x8 vf = ld16(&KV[cur][1][(dh * 32 + l31) * 64 + (((ks * 2 + hi) ^ swz) * 8)]);
        accO[dh] = __builtin_amdgcn_mfma_f32_32x32x16_bf16(vf, pb[ks], accO[dh], 0, 0, 0);
      }
    __builtin_amdgcn_s_setprio(0);
  }

  const float inv = 1.f / lsum;
  const int b = bh >> 4, h = bh & 15;
  u16* crow = ctx + ((size_t)b * S_ + q0 + l31) * DM_ + h * DK_;
#pragma unroll
  for (int dh = 0; dh < 2; ++dh)
#pragma unroll
    for (int g = 0; g < 4; ++g) {
      u16x4 o;
#pragma unroll
      for (int r = 0; r < 4; ++r) o[r] = f2bf(accO[dh][g * 4 + r] * inv);
      *(u16x4*)(crow + dh * 32 + g * 8 + hi * 4) = o;
    }
}

// ---------------- launcher ----------------
// ws high-water: 4 weights (4x2.1MB) + Qh/Kh/Vt (3x16.8) + ctx (16.8) = 75.5 MB
extern "C" void kernel_launch(void* const* d_in, const int* in_sizes, int n_in,
                              void* d_out, int out_size, void* d_ws, size_t ws_size,
                              hipStream_t stream) {
  const float* q  = (const float*)d_in[0];
  const float* k  = (const float*)d_in[1];
  const float* v  = (const float*)d_in[2];
  const float* Wq = (const float*)d_in[3];
  const float* Wk = (const float*)d_in[4];
  const float* Wv = (const float*)d_in[5];
  const float* Wo = (const float*)d_in[6];

  char* ws = (char*)d_ws;
  const size_t SZX = (size_t)M_ * DM_ * 2;   // 16.78 MB bf16 activation
  const size_t SZW = (size_t)DM_ * DM_ * 2;  // 2.10 MB bf16 weight
  u16* Wqt = (u16*)(ws);
  u16* Wkt = (u16*)(ws + SZW);
  u16* Wvt = (u16*)(ws + 2 * SZW);
  u16* Wot = (u16*)(ws + 3 * SZW);
  u16* Qh  = (u16*)(ws + 4 * SZW);
  u16* Kh  = (u16*)(ws + 4 * SZW + SZX);
  u16* Vt  = (u16*)(ws + 4 * SZW + 2 * SZX);
  u16* ctx = (u16*)(ws + 4 * SZW + 3 * SZX);

  wtrans_kernel<<<dim3(16, 16), 256, 0, stream>>>(Wq, Wqt);
  wtrans_kernel<<<dim3(16, 16), 256, 0, stream>>>(Wk, Wkt);
  wtrans_kernel<<<dim3(16, 16), 256, 0, stream>>>(Wv, Wvt);
  wtrans_kernel<<<dim3(16, 16), 256, 0, stream>>>(Wo, Wot);

  // batched QKV: 3 inputs x 64 m-blocks x 8 n-blocks = 1536 blocks (6/CU)
  gemm128<0><<<dim3(1536), 256, 0, stream>>>(q, k, v, nullptr, Wqt, Wkt, Wvt, Qh, Kh, Vt);

  attn_kernel<<<dim3(16, 64), 256, 0, stream>>>(Qh, Kh, Vt, ctx);

  // out-proj: 64 m-blocks x 8 n-blocks = 512 blocks (2/CU exactly)
  gemm128<1><<<dim3(512), 256, 0, stream>>>(nullptr, nullptr, nullptr, ctx,
                                            Wot, nullptr, nullptr, d_out, nullptr, nullptr);
}

// Round 10
// 364.152 us; speedup vs baseline: 1.0676x; 1.0676x over previous
//
#include <hip/hip_runtime.h>
#include <hip/hip_bf16.h>

typedef unsigned short u16;
typedef __attribute__((ext_vector_type(8))) short bf16x8;   // 8 bf16 = 4 VGPRs (MFMA A/B operand)
typedef __attribute__((ext_vector_type(4))) float f32x4;    // 16x16 MFMA C/D
typedef __attribute__((ext_vector_type(16))) float f32x16;  // 32x32 MFMA C/D
typedef __attribute__((ext_vector_type(4))) u16 u16x4;
typedef __attribute__((ext_vector_type(2))) int i32x2;
typedef __attribute__((ext_vector_type(4))) int i32x4;

#define DEV __device__ __forceinline__

constexpr int B_ = 4, S_ = 2048, H_ = 16, DK_ = 64, DM_ = 1024;
constexpr int M_ = B_ * S_;  // 8192 rows per GEMM

DEV u16 f2bf(float x) {  // RNE fp32 -> bf16
  union { float f; unsigned u; } v; v.f = x;
  return (u16)((v.u + 0x7fffu + ((v.u >> 16) & 1u)) >> 16);
}

DEV bf16x8 ld16(const u16* p) { return *(const bf16x8*)p; }

DEV void g2l16(const void* g, void* l) {  // async global->LDS, 16B/lane, wave-uniform dest
  __builtin_amdgcn_global_load_lds((const __attribute__((address_space(1))) void*)g,
                                   (__attribute__((address_space(3))) void*)l, 16, 0, 0);
}

DEV int cvtpk(float lo, float hi) {  // packed bf16 pair (RNE)
  int r;
  asm("v_cvt_pk_bf16_f32 %0, %1, %2" : "=v"(r) : "v"(lo), "v"(hi));
  return r;
}

DEV i32x2 pl32swap(int a, int b) {
  return __builtin_amdgcn_permlane32_swap(a, b, false, false);
}

DEV float asf(int x) { return __builtin_bit_cast(float, x); }
DEV int asi(float x) { return __builtin_bit_cast(int, x); }

// ---------------- fp32 -> bf16 convert (4 elems/thread, exact coverage) ----------------
__global__ __launch_bounds__(256) void cvt_kernel(const float* __restrict__ in,
                                                  u16* __restrict__ out) {
  int i = (blockIdx.x * 256 + threadIdx.x) * 4;
  float4 v = *(const float4*)(in + i);
  u16x4 o; o[0] = f2bf(v.x); o[1] = f2bf(v.y); o[2] = f2bf(v.z); o[3] = f2bf(v.w);
  *(u16x4*)(out + i) = o;
}

// ---------------- weight transpose-convert: W[K][N] fp32 -> Wt[N][K] bf16 ----------------
__global__ __launch_bounds__(256) void wtrans_kernel(const float* __restrict__ W,
                                                     u16* __restrict__ Wt) {
  __shared__ u16 t[64][68];
  const int r0 = blockIdx.y * 64, c0 = blockIdx.x * 64;
  const int lr = threadIdx.x >> 4;
  const int lc = (threadIdx.x & 15) * 4;
#pragma unroll
  for (int i = 0; i < 4; ++i) {
    int row = i * 16 + lr;
    float4 v = *(const float4*)(W + (size_t)(r0 + row) * DM_ + c0 + lc);
    t[lc + 0][row] = f2bf(v.x); t[lc + 1][row] = f2bf(v.y);
    t[lc + 2][row] = f2bf(v.z); t[lc + 3][row] = f2bf(v.w);
  }
  __syncthreads();
#pragma unroll
  for (int i = 0; i < 4; ++i) {
    int c = i * 16 + lr;
    u16x4 o; o[0] = t[c][lc]; o[1] = t[c][lc + 1]; o[2] = t[c][lc + 2]; o[3] = t[c][lc + 3];
    *(u16x4*)(Wt + (size_t)(c0 + c) * DM_ + r0 + lc) = o;
  }
}

// ========== 128x128 GEMM, BK=64, 4 waves, pure-DMA A+B, lead-1 double-buffer ==========
// A = bf16 [8192][1024] via global_load_lds (no reg-staging, no fp32 traffic).
// OUT_MODE 0: fp32 [M][1024] row-major.  1: bf16 scatter [b][h][s][d].  2: [b][h][d][s].
// T2 involution swizzle: DMA source chunk cg = c8 ^ (row&7); reads XOR the same mask.
// 512 blocks (2/CU), bijective XCD swizzle.
template <int OUT_MODE>
__global__ __launch_bounds__(256, 2) void gemm128b(const u16* __restrict__ X,
                                                   const u16* __restrict__ Wt,
                                                   void* __restrict__ outp) {
  constexpr int K = 1024, NK = 16;  // 16 K-tiles of 64
  __shared__ u16 As[2][8192];       // [slot][128 rows][64 cols] bf16, 16KB/slot
  __shared__ u16 Bs[2][8192];
  const int tid = threadIdx.x;
  const int w = tid >> 6, lane = tid & 63;
  const int l15 = lane & 15, lg = (lane >> 4) & 3;
  const int sr = tid >> 3;          // staging row-within-32 (0..31)
  const int c8 = tid & 7;           // staging chunk (linear dest)
  const int cg = c8 ^ (sr & 7);     // swizzled source chunk (row&7 == sr&7)

  // bijective XCD swizzle (512 % 8 == 0)
  const int wg = blockIdx.x;
  const int cpx = gridDim.x >> 3;
  const int idx = (wg & 7) * cpx + (wg >> 3);
  const int mblk = idx >> 3, nblk = idx & 7;
  const int m0 = mblk * 128, n0 = nblk * 128;

  const int wm = (w >> 1) * 64, wn = (w & 1) * 64;
  f32x4 acc[4][4] = {};

  // prologue: stage K-tile 0 -> slot 0
#pragma unroll
  for (int j = 0; j < 4; ++j) {
    int r = j * 32 + sr;
    g2l16(Wt + (size_t)(n0 + r) * K + cg * 8, &Bs[0][(j * 32 + 8 * w) * 64]);
    g2l16(X + (size_t)(m0 + r) * K + cg * 8, &As[0][(j * 32 + 8 * w) * 64]);
  }

  for (int g = 0; g < NK; ++g) {
    // boundary: tile g landed (DMA issued a full compute phase ago)
    asm volatile("s_waitcnt vmcnt(0) lgkmcnt(0)" ::: "memory");
    __builtin_amdgcn_s_barrier();
    asm volatile("" ::: "memory");
    const int rs = g & 1, ws2 = (g + 1) & 1;
    const bool st = (g + 1) < NK;
    const int kt1 = (g + 1) * 64;

    // issue next-tile staging into the idle slot (waited at next boundary)
    if (st) {
#pragma unroll
      for (int j = 0; j < 4; ++j) {
        int r = j * 32 + sr;
        g2l16(Wt + (size_t)(n0 + r) * K + kt1 + cg * 8, &Bs[ws2][(j * 32 + 8 * w) * 64]);
        g2l16(X + (size_t)(m0 + r) * K + kt1 + cg * 8, &As[ws2][(j * 32 + 8 * w) * 64]);
      }
    }

    // compute: 2 k-slots x 16 MFMA, evenly-banked swizzled ds_read_b128
#pragma unroll
    for (int kk = 0; kk < 2; ++kk) {
      bf16x8 af[4], bfr[4];
      const int ck = (kk * 4 + lg) ^ (l15 & 7);
#pragma unroll
      for (int mf = 0; mf < 4; ++mf)
        af[mf] = ld16(&As[rs][(wm + mf * 16 + l15) * 64 + ck * 8]);
#pragma unroll
      for (int nf = 0; nf < 4; ++nf)
        bfr[nf] = ld16(&Bs[rs][(wn + nf * 16 + l15) * 64 + ck * 8]);
      __builtin_amdgcn_s_setprio(1);
#pragma unroll
      for (int mf = 0; mf < 4; ++mf)
#pragma unroll
        for (int nf = 0; nf < 4; ++nf)
          acc[mf][nf] = __builtin_amdgcn_mfma_f32_16x16x32_bf16(af[mf], bfr[nf], acc[mf][nf], 0, 0, 0);
      __builtin_amdgcn_s_setprio(0);
    }
  }

  // epilogue: C/D layout col=lane&15, row=(lane>>4)*4+r  [m89-verified]
#pragma unroll
  for (int mf = 0; mf < 4; ++mf)
#pragma unroll
    for (int nf = 0; nf < 4; ++nf) {
      if (OUT_MODE == 2) {
        int m = m0 + wm + mf * 16 + lg * 4;
        int n = n0 + wn + nf * 16 + l15;
        int b = m >> 11, s = m & 2047;
        int h = n >> 6, d = n & 63;
        u16x4 o;
#pragma unroll
        for (int r = 0; r < 4; ++r) o[r] = f2bf(acc[mf][nf][r]);
        *(u16x4*)((u16*)outp + ((size_t)(b * H_ + h) * DK_ + d) * S_ + s) = o;
      } else if (OUT_MODE == 1) {
#pragma unroll
        for (int r = 0; r < 4; ++r) {
          int m = m0 + wm + mf * 16 + lg * 4 + r;
          int n = n0 + wn + nf * 16 + l15;
          int b = m >> 11, s = m & 2047;
          int h = n >> 6, d = n & 63;
          ((u16*)outp)[((size_t)(b * H_ + h) * S_ + s) * DK_ + d] = f2bf(acc[mf][nf][r]);
        }
      } else {
#pragma unroll
        for (int r = 0; r < 4; ++r) {
          int m = m0 + wm + mf * 16 + lg * 4 + r;
          int n = n0 + wn + nf * 16 + l15;
          ((float*)outp)[(size_t)m * DM_ + n] = acc[mf][nf][r];
        }
      }
    }
}

// ---------------- flash attention: LDS-staged K/V (lead-1 dbuf) + in-reg softmax ----------
// (unchanged — measured 134.5us, MfmaUtil 21.9%, VALUBusy 69%)
__global__ __launch_bounds__(256, 4) void attn_kernel(const u16* __restrict__ Qh,
                                                      const u16* __restrict__ Kh,
                                                      const u16* __restrict__ Vt,
                                                      u16* __restrict__ ctx) {
  __shared__ u16 KV[2][2][4096];  // [slot][K/V][64 rows x 64 cols], 32 KB
  const int tid = threadIdx.x;
  const int lane = tid & 63, w = tid >> 6;
  const int l31 = lane & 31, hi = lane >> 5;
  const int bh = blockIdx.y;
  const int q0 = blockIdx.x * 128 + w * 32;

  const u16* Qb = Qh + (size_t)bh * S_ * DK_;
  const u16* Kb = Kh + (size_t)bh * S_ * DK_;
  const u16* Vb = Vt + (size_t)bh * DK_ * S_;

  const int srow = tid >> 3;
  const int cs = (tid & 7) ^ (srow & 7);
  const int dstoff = w * 512;

  bf16x8 qf[4];
#pragma unroll
  for (int ds = 0; ds < 4; ++ds)
    qf[ds] = ld16(Qb + (size_t)(q0 + l31) * DK_ + ds * 16 + hi * 8);

  f32x16 accO[2] = {};
  float mreg = -1e30f, lsum = 0.f;
  const float SC = 0.125f * 1.44269504088896f;
  const int swz = (l31 & 7);

#pragma unroll
  for (int j = 0; j < 2; ++j) {
    int r = j * 32 + srow;
    g2l16(Kb + (size_t)r * DK_ + cs * 8, &KV[0][0][j * 2048 + dstoff]);
    g2l16(Vb + (size_t)r * S_ + cs * 8, &KV[0][1][j * 2048 + dstoff]);
  }

  for (int i = 0; i < 32; ++i) {
    const int cur = i & 1, nxt = cur ^ 1;
    __syncthreads();
    if (i < 31) {
      const int kvn = (i + 1) * 64;
#pragma unroll
      for (int j = 0; j < 2; ++j) {
        int r = j * 32 + srow;
        g2l16(Kb + (size_t)(kvn + r) * DK_ + cs * 8, &KV[nxt][0][j * 2048 + dstoff]);
        g2l16(Vb + (size_t)r * S_ + kvn + cs * 8, &KV[nxt][1][j * 2048 + dstoff]);
      }
    }

    f32x16 accS[2] = {};
    __builtin_amdgcn_s_setprio(1);
#pragma unroll
    for (int t = 0; t < 2; ++t)
#pragma unroll
      for (int ds = 0; ds < 4; ++ds) {
        bf16x8 kf = ld16(&KV[cur][0][(t * 32 + l31) * 64 + (((ds * 2 + hi) ^ swz) * 8)]);
        accS[t] = __builtin_amdgcn_mfma_f32_32x32x16_bf16(kf, qf[ds], accS[t], 0, 0, 0);
      }
    __builtin_amdgcn_s_setprio(0);

    float a[8];
#pragma unroll
    for (int r = 0; r < 8; ++r)
      a[r] = fmaxf(fmaxf(accS[0][r], accS[1][r]), fmaxf(accS[0][r + 8], accS[1][r + 8]));
#pragma unroll
    for (int s = 4; s; s >>= 1)
#pragma unroll
      for (int r = 0; r < s; ++r) a[r] = fmaxf(a[r], a[r + s]);
    i32x2 mm = pl32swap(asi(a[0]), asi(a[0]));
    float mx = fmaxf(asf(mm.x), asf(mm.y)) * SC;
    if (__any(mx > mreg + 8.f)) {
      float mnew = fmaxf(mreg, mx);
      float scl = exp2f(mreg - mnew);
      mreg = mnew;
      lsum *= scl;
#pragma unroll
      for (int r = 0; r < 16; ++r) { accO[0][r] *= scl; accO[1][r] *= scl; }
    }
#pragma unroll
    for (int t = 0; t < 2; ++t)
#pragma unroll
      for (int r = 0; r < 16; ++r)
        accS[t][r] = exp2f(fmaf(accS[t][r], SC, -mreg));
#pragma unroll
    for (int r = 0; r < 8; ++r)
      a[r] = (accS[0][r] + accS[1][r]) + (accS[0][r + 8] + accS[1][r + 8]);
#pragma unroll
    for (int s = 4; s; s >>= 1)
#pragma unroll
      for (int r = 0; r < s; ++r) a[r] += a[r + s];
    i32x2 ss = pl32swap(asi(a[0]), asi(a[0]));
    lsum += asf(ss.x) + asf(ss.y);

    bf16x8 pb[4];
#pragma unroll
    for (int t = 0; t < 2; ++t) {
      i32x2 sA = pl32swap(cvtpk(accS[t][0], accS[t][1]), cvtpk(accS[t][4], accS[t][5]));
      i32x2 sB = pl32swap(cvtpk(accS[t][2], accS[t][3]), cvtpk(accS[t][6], accS[t][7]));
      i32x2 sC = pl32swap(cvtpk(accS[t][8], accS[t][9]), cvtpk(accS[t][12], accS[t][13]));
      i32x2 sD = pl32swap(cvtpk(accS[t][10], accS[t][11]), cvtpk(accS[t][14], accS[t][15]));
      union { i32x4 i; bf16x8 h; } u0, u1;
      u0.i = (i32x4){sA.x, sB.x, sA.y, sB.y};
      u1.i = (i32x4){sC.x, sD.x, sC.y, sD.y};
      pb[2 * t] = u0.h;
      pb[2 * t + 1] = u1.h;
    }

    __builtin_amdgcn_s_setprio(1);
#pragma unroll
    for (int ks = 0; ks < 4; ++ks)
#pragma unroll
      for (int dh = 0; dh < 2; ++dh) {
        bf16x8 vf = ld16(&KV[cur][1][(dh * 32 + l31) * 64 + (((ks * 2 + hi) ^ swz) * 8)]);
        accO[dh] = __builtin_amdgcn_mfma_f32_32x32x16_bf16(vf, pb[ks], accO[dh], 0, 0, 0);
      }
    __builtin_amdgcn_s_setprio(0);
  }

  const float inv = 1.f / lsum;
  const int b = bh >> 4, h = bh & 15;
  u16* crow = ctx + ((size_t)b * S_ + q0 + l31) * DM_ + h * DK_;
#pragma unroll
  for (int dh = 0; dh < 2; ++dh)
#pragma unroll
    for (int g = 0; g < 4; ++g) {
      u16x4 o;
#pragma unroll
      for (int r = 0; r < 4; ++r) o[r] = f2bf(accO[dh][g * 4 + r] * inv);
      *(u16x4*)(crow + dh * 32 + g * 8 + hi * 4) = o;
    }
}

// ---------------- launcher ----------------
// ws high-water: 4 weights (8.4) + xb (16.8) + Qh/Kh/Vt (50.3) = 75.5 MB (measured-safe)
extern "C" void kernel_launch(void* const* d_in, const int* in_sizes, int n_in,
                              void* d_out, int out_size, void* d_ws, size_t ws_size,
                              hipStream_t stream) {
  const float* q  = (const float*)d_in[0];
  const float* k  = (const float*)d_in[1];
  const float* v  = (const float*)d_in[2];
  const float* Wq = (const float*)d_in[3];
  const float* Wk = (const float*)d_in[4];
  const float* Wv = (const float*)d_in[5];
  const float* Wo = (const float*)d_in[6];

  char* ws = (char*)d_ws;
  const size_t SZX = (size_t)M_ * DM_ * 2;   // 16.78 MB bf16 activation
  const size_t SZW = (size_t)DM_ * DM_ * 2;  // 2.10 MB bf16 weight
  u16* Wqt = (u16*)(ws);
  u16* Wkt = (u16*)(ws + SZW);
  u16* Wvt = (u16*)(ws + 2 * SZW);
  u16* Wot = (u16*)(ws + 3 * SZW);
  u16* xb  = (u16*)(ws + 4 * SZW);            // q/k/v bf16 (sequential reuse), later ctx
  u16* Qh  = (u16*)(ws + 4 * SZW + SZX);
  u16* Kh  = (u16*)(ws + 4 * SZW + 2 * SZX);
  u16* Vt  = (u16*)(ws + 4 * SZW + 3 * SZX);
  u16* ctx = xb;  // xb free after V projection

  wtrans_kernel<<<dim3(16, 16), 256, 0, stream>>>(Wq, Wqt);
  wtrans_kernel<<<dim3(16, 16), 256, 0, stream>>>(Wk, Wkt);
  wtrans_kernel<<<dim3(16, 16), 256, 0, stream>>>(Wv, Wvt);
  wtrans_kernel<<<dim3(16, 16), 256, 0, stream>>>(Wo, Wot);

  cvt_kernel<<<8192, 256, 0, stream>>>(q, xb);
  gemm128b<1><<<dim3(512), 256, 0, stream>>>(xb, Wqt, Qh);
  cvt_kernel<<<8192, 256, 0, stream>>>(k, xb);
  gemm128b<1><<<dim3(512), 256, 0, stream>>>(xb, Wkt, Kh);
  cvt_kernel<<<8192, 256, 0, stream>>>(v, xb);
  gemm128b<2><<<dim3(512), 256, 0, stream>>>(xb, Wvt, Vt);

  attn_kernel<<<dim3(16, 64), 256, 0, stream>>>(Qh, Kh, Vt, ctx);

  gemm128b<0><<<dim3(512), 256, 0, stream>>>(ctx, Wot, d_out);
}